// Round 21
// baseline (65.444 us; speedup 1.0000x reference)
//
#include <hip/hip_runtime.h>
#include <math.h>

// Problem constants
#define TT 16384
#define HH 2048
#define EE 64
#define KK 8

#define TB 32                // tokens per block (2 token-halves x 16)
#define HC 64
#define NCH (HH / HC)        // 32 chunks
#define KSPLIT 4             // K-slices
#define CPS (NCH / KSPLIT)   // 8 chunks per slice
#define TOPC 10
#define MARGIN_REL 8e-5f

// Output layout (flat float32):
#define IDX_OFF ((size_t)TT * KK)
#define MAP_OFF ((size_t)2 * TT * KK)
#define AUX_OFF ((size_t)2 * TT * KK + (size_t)TT * EE)

// d_ws byte layout: W planes | nflag | list | recI | recF  (~2 MB total)
#define WSPLANE 131072
#define NFLAG_B  524288
#define LIST_B   524320
#define RECI_B   589856
#define RECF_B   1245216
#define NTILE (TT / TB)      // 512

typedef short bf16x8 __attribute__((ext_vector_type(8)));
typedef float f32x4  __attribute__((ext_vector_type(4)));

__device__ __forceinline__ unsigned short f2bf(float x) {
    unsigned int u = __float_as_uint(x);
    u += 0x7FFFu + ((u >> 16) & 1u);
    return (unsigned short)(u >> 16);
}
__device__ __forceinline__ float bf2f(unsigned short b) {
    return __uint_as_float(((unsigned int)b) << 16);
}
__device__ __forceinline__ void cvt4(const float4 v, ushort4* hi, ushort4* lo) {
    unsigned short h0 = f2bf(v.x), h1 = f2bf(v.y),
                   h2 = f2bf(v.z), h3 = f2bf(v.w);
    *hi = make_ushort4(h0, h1, h2, h3);
    *lo = make_ushort4(f2bf(v.x - bf2f(h0)), f2bf(v.y - bf2f(h1)),
                       f2bf(v.z - bf2f(h2)), f2bf(v.w - bf2f(h3)));
}

__global__ __launch_bounds__(256)
void prep_kernel(const float* __restrict__ gw, unsigned short* __restrict__ ws,
                 unsigned int* __restrict__ nflag)
{
    if (blockIdx.x == 0 && threadIdx.x == 0) *nflag = 0u;
    const int gid = blockIdx.x * 256 + threadIdx.x;
    const int e  = gid >> 9;
    const int k  = (gid & 511) * 4;
    float4 v = *(const float4*)(gw + (size_t)e * HH + k);
    ushort4 hi, lo;
    cvt4(v, &hi, &lo);
    const int off = (k >> 5) * 2048 + ((k >> 3) & 3) * 512 + e * 8 + (k & 7);
    *(ushort4*)(ws + off)           = hi;
    *(ushort4*)(ws + WSPLANE + off) = lo;
}

// 3 MFMA (bf16x3) into acc##ET from B tile ET (u=0: UOFF=0, u=1: UOFF=2048)
#define MM(ET, AH, AL, BP, UOFF)                                               \
  {                                                                            \
    bf16x8 Bh = *(const bf16x8*)((BP) + (UOFF) + (ET) * 128);                  \
    bf16x8 Bl = *(const bf16x8*)((BP) + (UOFF) + (ET) * 128 + WSPLANE);        \
    acc##ET = __builtin_amdgcn_mfma_f32_16x16x32_bf16(AH, Bl, acc##ET, 0,0,0); \
    acc##ET = __builtin_amdgcn_mfma_f32_16x16x32_bf16(AL, Bh, acc##ET, 0,0,0); \
    acc##ET = __builtin_amdgcn_mfma_f32_16x16x32_bf16(AH, Bh, acc##ET, 0,0,0); \
  }

// Wave-synchronous chunk (R19/R20-validated), prefetch distance 4 chunks:
// stage 4 slots, issue slot reload for C+4, 2 k-steps x 4 expert tiles.
#define CHUNKW(C, A0, A1, A2, A3)                                              \
  do {                                                                         \
    unsigned char* buf_ = wbuf + ((C) & 1) * 4096;                             \
    ushort4 hi_, lo_;                                                          \
    cvt4(A0, &hi_, &lo_);                                                      \
    *(ushort4*)(buf_ + wOff0) = hi_; *(ushort4*)(buf_ + 2048 + wOff0) = lo_;   \
    cvt4(A1, &hi_, &lo_);                                                      \
    *(ushort4*)(buf_ + wOff1) = hi_; *(ushort4*)(buf_ + 2048 + wOff1) = lo_;   \
    cvt4(A2, &hi_, &lo_);                                                      \
    *(ushort4*)(buf_ + wOff2) = hi_; *(ushort4*)(buf_ + 2048 + wOff2) = lo_;   \
    cvt4(A3, &hi_, &lo_);                                                      \
    *(ushort4*)(buf_ + wOff3) = hi_; *(ushort4*)(buf_ + 2048 + wOff3) = lo_;   \
    if ((C) + 4 < CPS) {                                                       \
      const float* hp_ = hgp + (c0 + (C) + 4) * HC;                            \
      A0 = *(const float4*)(hp_);      A1 = *(const float4*)(hp_ + 16);        \
      A2 = *(const float4*)(hp_ + 32); A3 = *(const float4*)(hp_ + 48);        \
    }                                                                          \
    const unsigned short* bp_ = bBase + (size_t)(2 * (c0 + (C))) * 2048;       \
    {                                                                          \
      bf16x8 Ah = *(const bf16x8*)(buf_ + aOff0);                              \
      bf16x8 Al = *(const bf16x8*)(buf_ + 2048 + aOff0);                       \
      MM(0, Ah, Al, bp_, 0) MM(1, Ah, Al, bp_, 0)                              \
      MM(2, Ah, Al, bp_, 0) MM(3, Ah, Al, bp_, 0)                              \
    }                                                                          \
    {                                                                          \
      bf16x8 Ah = *(const bf16x8*)(buf_ + aOff1);                              \
      bf16x8 Al = *(const bf16x8*)(buf_ + 2048 + aOff1);                       \
      MM(0, Ah, Al, bp_, 2048) MM(1, Ah, Al, bp_, 2048)                        \
      MM(2, Ah, Al, bp_, 2048) MM(3, Ah, Al, bp_, 2048)                        \
    }                                                                          \
  } while (0)

__global__ __launch_bounds__(512, 4)
void fused_gemm(const float* __restrict__ hidden,
                const float* __restrict__ bias,
                const unsigned short* __restrict__ wsbuf,
                unsigned int* __restrict__ nflag,
                unsigned int* __restrict__ list,
                int* __restrict__ recI,
                float* __restrict__ recF,
                float* __restrict__ out)
{
    // per-wave dbuf staging: 8 waves x 8192 B = 64 KB (red overlays after)
    __shared__ __align__(16) unsigned char smem[65536];

    const int tid  = threadIdx.x;
    const int w    = tid >> 6;       // 0..7
    const int g    = w >> 2;         // token-half 0/1
    const int s    = w & 3;          // K-slice
    const int lane = tid & 63;
    const int tile = blockIdx.x;
    const int tok0 = tile * TB;
    const int c0   = s * CPS;

    // staging coords: lane stages row hr (of this wave's 16-token half)
    const int hr = lane >> 2;        // 0..15
    const int q4 = lane & 3;
    const float* hgp = hidden + (size_t)(tok0 + g * 16 + hr) * HH + q4 * 4;
    unsigned char* wbuf = smem + w * 8192;
    const int key = (hr & 7) << 4;
    const int wOff0 = hr * 128 + (((q4 + 0)  * 8) ^ key);
    const int wOff1 = hr * 128 + (((q4 + 4)  * 8) ^ key);
    const int wOff2 = hr * 128 + (((q4 + 8)  * 8) ^ key);
    const int wOff3 = hr * 128 + (((q4 + 12) * 8) ^ key);

    // fragment coords (R14-validated formulas, wave-local buffer)
    const int rx = lane & 15;
    const int kq = lane >> 4;
    const int aOff0 = rx * 128 + ((kq * 16) ^ ((rx & 7) << 4));
    const int aOff1 = aOff0 ^ 64;
    const unsigned short* bBase = wsbuf + kq * 512 + rx * 8;

    f32x4 acc0 = {0.f,0.f,0.f,0.f}, acc1 = {0.f,0.f,0.f,0.f};
    f32x4 acc2 = {0.f,0.f,0.f,0.f}, acc3 = {0.f,0.f,0.f,0.f};

    // 4-deep prefetch ring (static names, rule #20)
    float4 pA0, pA1, pA2, pA3, pB0, pB1, pB2, pB3;
    float4 pC0, pC1, pC2, pC3, pD0, pD1, pD2, pD3;
    {
        const float* hp = hgp + (c0 + 0) * HC;
        pA0 = *(const float4*)(hp);      pA1 = *(const float4*)(hp + 16);
        pA2 = *(const float4*)(hp + 32); pA3 = *(const float4*)(hp + 48);
        hp = hgp + (c0 + 1) * HC;
        pB0 = *(const float4*)(hp);      pB1 = *(const float4*)(hp + 16);
        pB2 = *(const float4*)(hp + 32); pB3 = *(const float4*)(hp + 48);
        hp = hgp + (c0 + 2) * HC;
        pC0 = *(const float4*)(hp);      pC1 = *(const float4*)(hp + 16);
        pC2 = *(const float4*)(hp + 32); pC3 = *(const float4*)(hp + 48);
        hp = hgp + (c0 + 3) * HC;
        pD0 = *(const float4*)(hp);      pD1 = *(const float4*)(hp + 16);
        pD2 = *(const float4*)(hp + 32); pD3 = *(const float4*)(hp + 48);
    }

    for (int c = 0; c < CPS; c += 4) {
        CHUNKW(c,     pA0, pA1, pA2, pA3);
        CHUNKW(c + 1, pB0, pB1, pB2, pB3);
        CHUNKW(c + 2, pC0, pC1, pC2, pC3);
        CHUNKW(c + 3, pD0, pD1, pD2, pD3);
    }

    // ---- cross-wave reduce: partials to LDS overlay ----
    __syncthreads();                  // all waves done with staging buffers
    float* red = (float*)smem;        // [8 waves][16 tok][68] = 34816 B
    {
        float* rw = red + w * 1088;
        #pragma unroll
        for (int r = 0; r < 4; ++r) {
            const int row = (4 * kq + r) * 68 + rx;
            rw[row +  0] = acc0[r];
            rw[row + 16] = acc1[r];
            rw[row + 32] = acc2[r];
            rw[row + 48] = acc3[r];
        }
    }
    __syncthreads();

    // ---- epilogue: 16 lanes per token, 32 tokens (512 threads) ----
    const int t   = tid >> 4;        // 0..31
    const int q   = tid & 15;
    const int tok = tok0 + t;
    const int gh  = t >> 4;          // token-half of this token
    const int tl  = t & 15;          // local token within half

    float lv[4];
    #pragma unroll
    for (int i = 0; i < 4; ++i) {
        const int o = tl * 68 + q + 16 * i;
        const float* rb = red + (size_t)(gh * 4) * 1088;
        lv[i] = (rb[o] + rb[1088 + o]) + (rb[2176 + o] + rb[3264 + o]);
    }

    float mx = lv[0];
    #pragma unroll
    for (int i = 1; i < 4; ++i) mx = fmaxf(mx, lv[i]);
    #pragma unroll
    for (int sh = 1; sh < 16; sh <<= 1) mx = fmaxf(mx, __shfl_xor(mx, sh, 64));

    float ex[4], psum = 0.0f;
    #pragma unroll
    for (int i = 0; i < 4; ++i) { ex[i] = expf(lv[i] - mx); psum += ex[i]; }
    #pragma unroll
    for (int sh = 1; sh < 16; sh <<= 1) psum += __shfl_xor(psum, sh, 64);
    const float inv = 1.0f / psum;

    float pr[4], selv[4];
    #pragma unroll
    for (int i = 0; i < 4; ++i) {
        pr[i]   = ex[i] * inv;
        selv[i] = pr[i] + bias[q + 16 * i];
    }

    float ws_[TOPC], wp[TOPC];
    int   wi[TOPC];
    #pragma unroll
    for (int k = 0; k < TOPC; ++k) {
        float bs = selv[0], bp = pr[0];
        int bi = q;
        #pragma unroll
        for (int i = 1; i < 4; ++i)
            if (selv[i] > bs) { bs = selv[i]; bp = pr[i]; bi = q + 16 * i; }
        #pragma unroll
        for (int sh = 1; sh < 16; sh <<= 1) {
            float os = __shfl_xor(bs, sh, 64);
            float op = __shfl_xor(bp, sh, 64);
            int   ob = __shfl_xor(bi, sh, 64);
            if (os > bs || (os == bs && ob < bi)) { bs = os; bp = op; bi = ob; }
        }
        ws_[k] = bs; wp[k] = bp; wi[k] = bi;
        #pragma unroll
        for (int i = 0; i < 4; ++i)
            if (q + 16 * i == bi) selv[i] = -INFINITY;
    }

    bool flag = false;
    #pragma unroll
    for (int k = 0; k < 8; ++k)
        flag = flag || (ws_[k] - ws_[k + 1] <
                        (ws_[k] + ws_[k + 1]) * MARGIN_REL + 1e-12f);

    {
        int   mywi = wi[0];
        float mywp = wp[0];
        #pragma unroll
        for (int k = 1; k < TOPC; ++k)
            if (q == k) { mywi = wi[k]; mywp = wp[k]; }
        if (flag && q < TOPC) {
            recI[(size_t)tok * 10 + q] = mywi;
            recF[(size_t)tok * 12 + q] = mywp;
        }
        if (flag && q == 0) {
            recF[(size_t)tok * 12 + 10] = mx;
            recF[(size_t)tok * 12 + 11] = inv;
            unsigned int o = atomicAdd(nflag, 1u);
            list[o] = (unsigned int)tok;
        }
    }

    int oi = wi[0];
    float opf = wp[0];
    #pragma unroll
    for (int k = 1; k < 8; ++k)
        if (q == k) { oi = wi[k]; opf = wp[k]; }

    float ps = 0.0f;
    #pragma unroll
    for (int k = 0; k < 8; ++k) ps += wp[k];
    const float rinv = 1.0f / (ps + 1e-9f);

    if (q < KK) {
        out[(size_t)tok * KK + q]           = opf * rinv;
        out[IDX_OFF + (size_t)tok * KK + q] = (float)oi;
    }

    unsigned long long mk = 0ull;
    #pragma unroll
    for (int k = 0; k < 8; ++k) mk |= (1ull << wi[k]);

    {
        float4 a;
        a.x = ((mk >> (4 * q + 0)) & 1ull) ? 1.0f : 0.0f;
        a.y = ((mk >> (4 * q + 1)) & 1ull) ? 1.0f : 0.0f;
        a.z = ((mk >> (4 * q + 2)) & 1ull) ? 1.0f : 0.0f;
        a.w = ((mk >> (4 * q + 3)) & 1ull) ? 1.0f : 0.0f;
        *(float4*)(out + MAP_OFF + (size_t)tok * EE + 4 * q) = a;
    }

    if (tile == 0 && tid == 0) out[AUX_OFF] = 0.0f;
}

// ---- fixup: one 256-thread block per flagged token (R17-validated) ----
__global__ __launch_bounds__(256, 4)
void fixup_kernel(const float* __restrict__ hidden,
                  const float* __restrict__ gate_w,
                  const float* __restrict__ bias,
                  const unsigned int* __restrict__ nflag,
                  const unsigned int* __restrict__ list,
                  const int* __restrict__ recI,
                  const float* __restrict__ recF,
                  float* __restrict__ out)
{
    __shared__ double redL[4][12];

    const int tid  = threadIdx.x;
    const int wv   = tid >> 6;
    const int lane = tid & 63;
    const unsigned int nf = *nflag;

    for (unsigned int i = blockIdx.x; i < nf; i += gridDim.x) {
        const int tok = (int)list[i];

        int   wk[TOPC];
        #pragma unroll
        for (int k = 0; k < TOPC; ++k) wk[k] = recI[(size_t)tok * 10 + k];
        const float mx  = recF[(size_t)tok * 12 + 10];
        const float inv = recF[(size_t)tok * 12 + 11];

        const float* hp = hidden + (size_t)tok * HH + tid * 8;
        float4 ha = *(const float4*)(hp);
        float4 hb = *(const float4*)(hp + 4);
        double h0 = ha.x, h1 = ha.y, h2 = ha.z, h3 = ha.w;
        double h4 = hb.x, h5 = hb.y, h6 = hb.z, h7 = hb.w;

        double l64[TOPC];
        #pragma unroll
        for (int k = 0; k < TOPC; ++k) {
            const float* wpt = gate_w + (size_t)wk[k] * HH + tid * 8;
            float4 wa = *(const float4*)(wpt);
            float4 wb = *(const float4*)(wpt + 4);
            double sacc = 0.0;
            sacc = fma(h0, (double)wa.x, sacc); sacc = fma(h1, (double)wa.y, sacc);
            sacc = fma(h2, (double)wa.z, sacc); sacc = fma(h3, (double)wa.w, sacc);
            sacc = fma(h4, (double)wb.x, sacc); sacc = fma(h5, (double)wb.y, sacc);
            sacc = fma(h6, (double)wb.z, sacc); sacc = fma(h7, (double)wb.w, sacc);
            l64[k] = sacc;
        }
        #pragma unroll
        for (int k = 0; k < TOPC; ++k)
            #pragma unroll
            for (int sh = 1; sh < 64; sh <<= 1)
                l64[k] += __shfl_xor(l64[k], sh, 64);
        if (lane == 0)
            #pragma unroll
            for (int k = 0; k < TOPC; ++k) redL[wv][k] = l64[k];
        __syncthreads();

        if (tid == 0) {
            double s64[TOPC];
            int    wi2[TOPC];
            float  wp2[TOPC];
            #pragma unroll
            for (int k = 0; k < TOPC; ++k) {
                double lk = redL[0][k] + redL[1][k] + redL[2][k] + redL[3][k];
                s64[k] = exp(lk - (double)mx) * (double)inv +
                         (double)bias[wk[k]];
                wi2[k] = wk[k];
                wp2[k] = recF[(size_t)tok * 12 + k];
            }
            #pragma unroll
            for (int a = 0; a < 8; ++a) {
                #pragma unroll
                for (int b = a + 1; b < TOPC; ++b) {
                    bool sw = (s64[b] > s64[a]) ||
                              (s64[b] == s64[a] && wi2[b] < wi2[a]);
                    if (sw) {
                        double td = s64[a]; s64[a] = s64[b]; s64[b] = td;
                        int    ti = wi2[a]; wi2[a] = wi2[b]; wi2[b] = ti;
                        float  tp = wp2[a]; wp2[a] = wp2[b]; wp2[b] = tp;
                    }
                }
            }
            float ps = 0.0f;
            #pragma unroll
            for (int k = 0; k < 8; ++k) ps += wp2[k];
            const float rinv = 1.0f / (ps + 1e-9f);
            unsigned long long mk = 0ull;
            #pragma unroll
            for (int k = 0; k < 8; ++k) {
                out[(size_t)tok * KK + k]           = wp2[k] * rinv;
                out[IDX_OFF + (size_t)tok * KK + k] = (float)wi2[k];
                mk |= (1ull << wi2[k]);
            }
            for (int e = 0; e < EE; ++e)
                out[MAP_OFF + (size_t)tok * EE + e] =
                    ((mk >> e) & 1ull) ? 1.0f : 0.0f;
        }
        __syncthreads();
    }
}

extern "C" void kernel_launch(void* const* d_in, const int* in_sizes, int n_in,
                              void* d_out, int out_size, void* d_ws, size_t ws_size,
                              hipStream_t stream) {
    const float* hidden = (const float*)d_in[0];
    const float* gate_w = (const float*)d_in[1];
    const float* bias   = (const float*)d_in[2];
    float* out = (float*)d_out;

    char* wsb = (char*)d_ws;
    unsigned short* wplanes = (unsigned short*)wsb;
    unsigned int* nflag = (unsigned int*)(wsb + NFLAG_B);
    unsigned int* list  = (unsigned int*)(wsb + LIST_B);
    int*          recI  = (int*)(wsb + RECI_B);
    float*        recF  = (float*)(wsb + RECF_B);

    prep_kernel<<<128, 256, 0, stream>>>(gate_w, wplanes, nflag);
    fused_gemm<<<NTILE, 512, 0, stream>>>(hidden, bias, wplanes, nflag, list,
                                          recI, recF, out);
    fixup_kernel<<<256, 256, 0, stream>>>(hidden, gate_w, bias, nflag, list,
                                          recI, recF, out);
}

// Round 22
// 61.871 us; speedup vs baseline: 1.0578x; 1.0578x over previous
//
#include <hip/hip_runtime.h>
#include <math.h>

// Problem constants
#define TT 16384
#define HH 2048
#define EE 64
#define KK 8

#define TB 32                // tokens per block (2 token-halves x 16)
#define HC 64
#define NCH (HH / HC)        // 32 chunks
#define KSPLIT 4             // K-slices (one per wave-pair)
#define CPS (NCH / KSPLIT)   // 8 chunks per slice
#define TOPC 10
#define MARGIN_REL 8e-5f

// Output layout (flat float32):
#define IDX_OFF ((size_t)TT * KK)
#define MAP_OFF ((size_t)2 * TT * KK)
#define AUX_OFF ((size_t)2 * TT * KK + (size_t)TT * EE)

// d_ws byte layout: W planes | nflag | list | recI | recF  (~2 MB total)
#define WSPLANE 131072
#define NFLAG_B  524288
#define LIST_B   524320
#define RECI_B   589856
#define RECF_B   1245216
#define NTILE (TT / TB)      // 512

typedef short bf16x8 __attribute__((ext_vector_type(8)));
typedef float f32x4  __attribute__((ext_vector_type(4)));

__device__ __forceinline__ unsigned short f2bf(float x) {
    unsigned int u = __float_as_uint(x);
    u += 0x7FFFu + ((u >> 16) & 1u);
    return (unsigned short)(u >> 16);
}
__device__ __forceinline__ float bf2f(unsigned short b) {
    return __uint_as_float(((unsigned int)b) << 16);
}
__device__ __forceinline__ void cvt4(const float4 v, ushort4* hi, ushort4* lo) {
    unsigned short h0 = f2bf(v.x), h1 = f2bf(v.y),
                   h2 = f2bf(v.z), h3 = f2bf(v.w);
    *hi = make_ushort4(h0, h1, h2, h3);
    *lo = make_ushort4(f2bf(v.x - bf2f(h0)), f2bf(v.y - bf2f(h1)),
                       f2bf(v.z - bf2f(h2)), f2bf(v.w - bf2f(h3)));
}

__global__ __launch_bounds__(256)
void prep_kernel(const float* __restrict__ gw, unsigned short* __restrict__ ws,
                 unsigned int* __restrict__ nflag)
{
    if (blockIdx.x == 0 && threadIdx.x == 0) *nflag = 0u;
    const int gid = blockIdx.x * 256 + threadIdx.x;
    const int e  = gid >> 9;
    const int k  = (gid & 511) * 4;
    float4 v = *(const float4*)(gw + (size_t)e * HH + k);
    ushort4 hi, lo;
    cvt4(v, &hi, &lo);
    const int off = (k >> 5) * 2048 + ((k >> 3) & 3) * 512 + e * 8 + (k & 7);
    *(ushort4*)(ws + off)           = hi;
    *(ushort4*)(ws + WSPLANE + off) = lo;
}

// 3 MFMA (bf16x3) into acc##ET from B tile ET (u=0: UOFF=0, u=1: UOFF=2048)
#define MM(ET, AH, AL, BP, UOFF)                                               \
  {                                                                            \
    bf16x8 Bh = *(const bf16x8*)((BP) + (UOFF) + (ET) * 128);                  \
    bf16x8 Bl = *(const bf16x8*)((BP) + (UOFF) + (ET) * 128 + WSPLANE);        \
    acc##ET = __builtin_amdgcn_mfma_f32_16x16x32_bf16(AH, Bl, acc##ET, 0,0,0); \
    acc##ET = __builtin_amdgcn_mfma_f32_16x16x32_bf16(AL, Bh, acc##ET, 0,0,0); \
    acc##ET = __builtin_amdgcn_mfma_f32_16x16x32_bf16(AH, Bh, acc##ET, 0,0,0); \
  }

// Wave-synchronous chunk (R19/R20-validated): stage 4 slots, prefetch C+2,
// 2 k-steps x 4 expert tiles. No __syncthreads — per-wave LDS ops in-order.
#define CHUNKW(C, A0, A1, A2, A3)                                              \
  do {                                                                         \
    unsigned char* buf_ = wbuf + ((C) & 1) * 4096;                             \
    ushort4 hi_, lo_;                                                          \
    cvt4(A0, &hi_, &lo_);                                                      \
    *(ushort4*)(buf_ + wOff0) = hi_; *(ushort4*)(buf_ + 2048 + wOff0) = lo_;   \
    cvt4(A1, &hi_, &lo_);                                                      \
    *(ushort4*)(buf_ + wOff1) = hi_; *(ushort4*)(buf_ + 2048 + wOff1) = lo_;   \
    cvt4(A2, &hi_, &lo_);                                                      \
    *(ushort4*)(buf_ + wOff2) = hi_; *(ushort4*)(buf_ + 2048 + wOff2) = lo_;   \
    cvt4(A3, &hi_, &lo_);                                                      \
    *(ushort4*)(buf_ + wOff3) = hi_; *(ushort4*)(buf_ + 2048 + wOff3) = lo_;   \
    if ((C) + 2 < CPS) {                                                       \
      const float* hp_ = hgp + (c0 + (C) + 2) * HC;                            \
      A0 = *(const float4*)(hp_);      A1 = *(const float4*)(hp_ + 16);        \
      A2 = *(const float4*)(hp_ + 32); A3 = *(const float4*)(hp_ + 48);        \
    }                                                                          \
    const unsigned short* bp_ = bBase + (size_t)(2 * (c0 + (C))) * 2048;       \
    {                                                                          \
      bf16x8 Ah = *(const bf16x8*)(buf_ + aOff0);                              \
      bf16x8 Al = *(const bf16x8*)(buf_ + 2048 + aOff0);                       \
      MM(0, Ah, Al, bp_, 0) MM(1, Ah, Al, bp_, 0)                              \
      MM(2, Ah, Al, bp_, 0) MM(3, Ah, Al, bp_, 0)                              \
    }                                                                          \
    {                                                                          \
      bf16x8 Ah = *(const bf16x8*)(buf_ + aOff1);                              \
      bf16x8 Al = *(const bf16x8*)(buf_ + 2048 + aOff1);                       \
      MM(0, Ah, Al, bp_, 2048) MM(1, Ah, Al, bp_, 2048)                        \
      MM(2, Ah, Al, bp_, 2048) MM(3, Ah, Al, bp_, 2048)                        \
    }                                                                          \
  } while (0)

__global__ __launch_bounds__(512, 4)
void fused_gemm(const float* __restrict__ hidden,
                const float* __restrict__ bias,
                const unsigned short* __restrict__ wsbuf,
                unsigned int* __restrict__ nflag,
                unsigned int* __restrict__ list,
                int* __restrict__ recI,
                float* __restrict__ recF,
                float* __restrict__ out)
{
    // per-wave dbuf staging: 8 waves x 8192 B = 64 KB (red overlays after)
    __shared__ __align__(16) unsigned char smem[65536];

    const int tid  = threadIdx.x;
    const int w    = tid >> 6;       // 0..7
    const int g    = w >> 2;         // token-half 0/1
    const int s    = w & 3;          // K-slice
    const int lane = tid & 63;
    const int tile = blockIdx.x;
    const int tok0 = tile * TB;
    const int c0   = s * CPS;

    // staging coords: lane stages row hr (of this wave's 16-token half)
    const int hr = lane >> 2;        // 0..15
    const int q4 = lane & 3;
    const float* hgp = hidden + (size_t)(tok0 + g * 16 + hr) * HH + q4 * 4;
    unsigned char* wbuf = smem + w * 8192;
    const int key = (hr & 7) << 4;
    const int wOff0 = hr * 128 + (((q4 + 0)  * 8) ^ key);
    const int wOff1 = hr * 128 + (((q4 + 4)  * 8) ^ key);
    const int wOff2 = hr * 128 + (((q4 + 8)  * 8) ^ key);
    const int wOff3 = hr * 128 + (((q4 + 12) * 8) ^ key);

    // fragment coords (R14-validated formulas, wave-local buffer)
    const int rx = lane & 15;
    const int kq = lane >> 4;
    const int aOff0 = rx * 128 + ((kq * 16) ^ ((rx & 7) << 4));
    const int aOff1 = aOff0 ^ 64;
    const unsigned short* bBase = wsbuf + kq * 512 + rx * 8;

    f32x4 acc0 = {0.f,0.f,0.f,0.f}, acc1 = {0.f,0.f,0.f,0.f};
    f32x4 acc2 = {0.f,0.f,0.f,0.f}, acc3 = {0.f,0.f,0.f,0.f};

    // 2-deep prefetch ring (static names)
    float4 a0, a1, a2, a3, b0, b1, b2, b3;
    {
        const float* hp = hgp + c0 * HC;
        a0 = *(const float4*)(hp);      a1 = *(const float4*)(hp + 16);
        a2 = *(const float4*)(hp + 32); a3 = *(const float4*)(hp + 48);
        const float* hq = hgp + (c0 + 1) * HC;
        b0 = *(const float4*)(hq);      b1 = *(const float4*)(hq + 16);
        b2 = *(const float4*)(hq + 32); b3 = *(const float4*)(hq + 48);
    }

    for (int c = 0; c < CPS; c += 2) {
        CHUNKW(c,     a0, a1, a2, a3);
        CHUNKW(c + 1, b0, b1, b2, b3);
    }

    // ---- cross-wave reduce: partials to LDS overlay ----
    __syncthreads();                  // all waves done with staging buffers
    float* red = (float*)smem;        // [8 waves][16 tok][68] = 34816 B
    {
        float* rw = red + w * 1088;
        #pragma unroll
        for (int r = 0; r < 4; ++r) {
            const int row = (4 * kq + r) * 68 + rx;
            rw[row +  0] = acc0[r];
            rw[row + 16] = acc1[r];
            rw[row + 32] = acc2[r];
            rw[row + 48] = acc3[r];
        }
    }
    __syncthreads();

    // ---- epilogue: 16 lanes per token, 32 tokens (512 threads) ----
    const int t   = tid >> 4;        // 0..31
    const int q   = tid & 15;
    const int tok = tok0 + t;
    const int gh  = t >> 4;          // token-half of this token
    const int tl  = t & 15;          // local token within half

    float lv[4];
    #pragma unroll
    for (int i = 0; i < 4; ++i) {
        const int o = tl * 68 + q + 16 * i;
        const float* rb = red + (size_t)(gh * 4) * 1088;
        lv[i] = (rb[o] + rb[1088 + o]) + (rb[2176 + o] + rb[3264 + o]);
    }

    float mx = lv[0];
    #pragma unroll
    for (int i = 1; i < 4; ++i) mx = fmaxf(mx, lv[i]);
    #pragma unroll
    for (int sh = 1; sh < 16; sh <<= 1) mx = fmaxf(mx, __shfl_xor(mx, sh, 64));

    float ex[4], psum = 0.0f;
    #pragma unroll
    for (int i = 0; i < 4; ++i) { ex[i] = expf(lv[i] - mx); psum += ex[i]; }
    #pragma unroll
    for (int sh = 1; sh < 16; sh <<= 1) psum += __shfl_xor(psum, sh, 64);
    const float inv = 1.0f / psum;

    float pr[4], selv[4];
    #pragma unroll
    for (int i = 0; i < 4; ++i) {
        pr[i]   = ex[i] * inv;
        selv[i] = pr[i] + bias[q + 16 * i];
    }

    float ws_[TOPC], wp[TOPC];
    int   wi[TOPC];
    #pragma unroll
    for (int k = 0; k < TOPC; ++k) {
        float bs = selv[0], bp = pr[0];
        int bi = q;
        #pragma unroll
        for (int i = 1; i < 4; ++i)
            if (selv[i] > bs) { bs = selv[i]; bp = pr[i]; bi = q + 16 * i; }
        #pragma unroll
        for (int sh = 1; sh < 16; sh <<= 1) {
            float os = __shfl_xor(bs, sh, 64);
            float op = __shfl_xor(bp, sh, 64);
            int   ob = __shfl_xor(bi, sh, 64);
            if (os > bs || (os == bs && ob < bi)) { bs = os; bp = op; bi = ob; }
        }
        ws_[k] = bs; wp[k] = bp; wi[k] = bi;
        #pragma unroll
        for (int i = 0; i < 4; ++i)
            if (q + 16 * i == bi) selv[i] = -INFINITY;
    }

    bool flag = false;
    #pragma unroll
    for (int k = 0; k < 8; ++k)
        flag = flag || (ws_[k] - ws_[k + 1] <
                        (ws_[k] + ws_[k + 1]) * MARGIN_REL + 1e-12f);

    {
        int   mywi = wi[0];
        float mywp = wp[0];
        #pragma unroll
        for (int k = 1; k < TOPC; ++k)
            if (q == k) { mywi = wi[k]; mywp = wp[k]; }
        if (flag && q < TOPC) {
            recI[(size_t)tok * 10 + q] = mywi;
            recF[(size_t)tok * 12 + q] = mywp;
        }
        if (flag && q == 0) {
            recF[(size_t)tok * 12 + 10] = mx;
            recF[(size_t)tok * 12 + 11] = inv;
            unsigned int o = atomicAdd(nflag, 1u);
            list[o] = (unsigned int)tok;
        }
    }

    int oi = wi[0];
    float opf = wp[0];
    #pragma unroll
    for (int k = 1; k < 8; ++k)
        if (q == k) { oi = wi[k]; opf = wp[k]; }

    float ps = 0.0f;
    #pragma unroll
    for (int k = 0; k < 8; ++k) ps += wp[k];
    const float rinv = 1.0f / (ps + 1e-9f);

    if (q < KK) {
        out[(size_t)tok * KK + q]           = opf * rinv;
        out[IDX_OFF + (size_t)tok * KK + q] = (float)oi;
    }

    unsigned long long mk = 0ull;
    #pragma unroll
    for (int k = 0; k < 8; ++k) mk |= (1ull << wi[k]);

    {
        float4 a;
        a.x = ((mk >> (4 * q + 0)) & 1ull) ? 1.0f : 0.0f;
        a.y = ((mk >> (4 * q + 1)) & 1ull) ? 1.0f : 0.0f;
        a.z = ((mk >> (4 * q + 2)) & 1ull) ? 1.0f : 0.0f;
        a.w = ((mk >> (4 * q + 3)) & 1ull) ? 1.0f : 0.0f;
        *(float4*)(out + MAP_OFF + (size_t)tok * EE + 4 * q) = a;
    }

    if (tile == 0 && tid == 0) out[AUX_OFF] = 0.0f;
}

// ---- fixup: one 256-thread block per flagged token (R17-validated) ----
__global__ __launch_bounds__(256, 4)
void fixup_kernel(const float* __restrict__ hidden,
                  const float* __restrict__ gate_w,
                  const float* __restrict__ bias,
                  const unsigned int* __restrict__ nflag,
                  const unsigned int* __restrict__ list,
                  const int* __restrict__ recI,
                  const float* __restrict__ recF,
                  float* __restrict__ out)
{
    __shared__ double redL[4][12];

    const int tid  = threadIdx.x;
    const int wv   = tid >> 6;
    const int lane = tid & 63;
    const unsigned int nf = *nflag;

    for (unsigned int i = blockIdx.x; i < nf; i += gridDim.x) {
        const int tok = (int)list[i];

        int   wk[TOPC];
        #pragma unroll
        for (int k = 0; k < TOPC; ++k) wk[k] = recI[(size_t)tok * 10 + k];
        const float mx  = recF[(size_t)tok * 12 + 10];
        const float inv = recF[(size_t)tok * 12 + 11];

        const float* hp = hidden + (size_t)tok * HH + tid * 8;
        float4 ha = *(const float4*)(hp);
        float4 hb = *(const float4*)(hp + 4);
        double h0 = ha.x, h1 = ha.y, h2 = ha.z, h3 = ha.w;
        double h4 = hb.x, h5 = hb.y, h6 = hb.z, h7 = hb.w;

        double l64[TOPC];
        #pragma unroll
        for (int k = 0; k < TOPC; ++k) {
            const float* wpt = gate_w + (size_t)wk[k] * HH + tid * 8;
            float4 wa = *(const float4*)(wpt);
            float4 wb = *(const float4*)(wpt + 4);
            double sacc = 0.0;
            sacc = fma(h0, (double)wa.x, sacc); sacc = fma(h1, (double)wa.y, sacc);
            sacc = fma(h2, (double)wa.z, sacc); sacc = fma(h3, (double)wa.w, sacc);
            sacc = fma(h4, (double)wb.x, sacc); sacc = fma(h5, (double)wb.y, sacc);
            sacc = fma(h6, (double)wb.z, sacc); sacc = fma(h7, (double)wb.w, sacc);
            l64[k] = sacc;
        }
        #pragma unroll
        for (int k = 0; k < TOPC; ++k)
            #pragma unroll
            for (int sh = 1; sh < 64; sh <<= 1)
                l64[k] += __shfl_xor(l64[k], sh, 64);
        if (lane == 0)
            #pragma unroll
            for (int k = 0; k < TOPC; ++k) redL[wv][k] = l64[k];
        __syncthreads();

        if (tid == 0) {
            double s64[TOPC];
            int    wi2[TOPC];
            float  wp2[TOPC];
            #pragma unroll
            for (int k = 0; k < TOPC; ++k) {
                double lk = redL[0][k] + redL[1][k] + redL[2][k] + redL[3][k];
                s64[k] = exp(lk - (double)mx) * (double)inv +
                         (double)bias[wk[k]];
                wi2[k] = wk[k];
                wp2[k] = recF[(size_t)tok * 12 + k];
            }
            #pragma unroll
            for (int a = 0; a < 8; ++a) {
                #pragma unroll
                for (int b = a + 1; b < TOPC; ++b) {
                    bool sw = (s64[b] > s64[a]) ||
                              (s64[b] == s64[a] && wi2[b] < wi2[a]);
                    if (sw) {
                        double td = s64[a]; s64[a] = s64[b]; s64[b] = td;
                        int    ti = wi2[a]; wi2[a] = wi2[b]; wi2[b] = ti;
                        float  tp = wp2[a]; wp2[a] = wp2[b]; wp2[b] = tp;
                    }
                }
            }
            float ps = 0.0f;
            #pragma unroll
            for (int k = 0; k < 8; ++k) ps += wp2[k];
            const float rinv = 1.0f / (ps + 1e-9f);
            unsigned long long mk = 0ull;
            #pragma unroll
            for (int k = 0; k < 8; ++k) {
                out[(size_t)tok * KK + k]           = wp2[k] * rinv;
                out[IDX_OFF + (size_t)tok * KK + k] = (float)wi2[k];
                mk |= (1ull << wi2[k]);
            }
            for (int e = 0; e < EE; ++e)
                out[MAP_OFF + (size_t)tok * EE + e] =
                    ((mk >> e) & 1ull) ? 1.0f : 0.0f;
        }
        __syncthreads();
    }
}

extern "C" void kernel_launch(void* const* d_in, const int* in_sizes, int n_in,
                              void* d_out, int out_size, void* d_ws, size_t ws_size,
                              hipStream_t stream) {
    const float* hidden = (const float*)d_in[0];
    const float* gate_w = (const float*)d_in[1];
    const float* bias   = (const float*)d_in[2];
    float* out = (float*)d_out;

    char* wsb = (char*)d_ws;
    unsigned short* wplanes = (unsigned short*)wsb;
    unsigned int* nflag = (unsigned int*)(wsb + NFLAG_B);
    unsigned int* list  = (unsigned int*)(wsb + LIST_B);
    int*          recI  = (int*)(wsb + RECI_B);
    float*        recF  = (float*)(wsb + RECF_B);

    prep_kernel<<<128, 256, 0, stream>>>(gate_w, wplanes, nflag);
    fused_gemm<<<NTILE, 512, 0, stream>>>(hidden, bias, wplanes, nflag, list,
                                          recI, recF, out);
    fixup_kernel<<<256, 256, 0, stream>>>(hidden, gate_w, bias, nflag, list,
                                          recI, recF, out);
}